// Round 3
// baseline (160.324 us; speedup 1.0000x reference)
//
#include <hip/hip_runtime.h>
#include <hip/hip_bf16.h>
#include <math.h>

// Problem dims
#define B_DIM 32
#define S_DIM 256
#define F_DIM 64
#define U_DIM 128
#define TOK   (B_DIM * S_DIM)   // 8192 tokens
#define KDIM  (F_DIM * U_DIM)   // 8192 reduction dim
#define N3    (3 * U_DIM)       // 384 fused output cols (elu|gate|proj)

// GEMM tiling
#define BM3    128
#define BK     64
#define KSPL   8
#define KRANGE (KDIM / KSPL)    // 1024
#define NST    (KRANGE / BK)    // 16
#define ASTR   72               // a_lds row stride (bf16), 16B-aligned

typedef __bf16 bf16x8 __attribute__((ext_vector_type(8)));
typedef float  f32x4  __attribute__((ext_vector_type(4)));

// tanh-approx GELU via exp2 folding:
// gelu(z) ~= z - z / (1 + 2^(z*(2.30234 + 0.102955 z^2)))   |err| < ~1e-3
__device__ __forceinline__ float gelu_fast(float z) {
    float t = z * z;
    float s = fmaf(0.1029551f, t, 2.3023457f);
    float e = __builtin_amdgcn_exp2f(z * s);
    float r = __builtin_amdgcn_rcpf(e + 1.0f);   // +inf -> 0
    return fmaf(-z, r, z);
}

// ---------------------------------------------------------------------------
// Kernel 1: pack W[k][n] f32 (3 mats) -> Bp[k/32][n(384)][k%32] bf16.
// grid = 3 * (KDIM/32), 256 threads.
// ---------------------------------------------------------------------------
__global__ __launch_bounds__(256) void vsn_prep3(
    const float* __restrict__ elu_w,
    const float* __restrict__ gate_w,
    const float* __restrict__ proj_w,
    __bf16* __restrict__ Bp)
{
    __shared__ float tile[32][U_DIM + 1];
    const int mat = blockIdx.x / (KDIM / 32);
    const int kb  = blockIdx.x % (KDIM / 32);
    const float* W = (mat == 0) ? elu_w : (mat == 1 ? gate_w : proj_w);
    const int t = threadIdx.x;

#pragma unroll
    for (int i = 0; i < 16; ++i) {
        int idx = i * 256 + t;
        int r = idx >> 7, c = idx & 127;
        tile[r][c] = W[(size_t)(kb * 32 + r) * U_DIM + c];
    }
    __syncthreads();
#pragma unroll
    for (int i = 0; i < 16; ++i) {
        int idx = i * 256 + t;
        int c = idx >> 5, r = idx & 31;
        Bp[((size_t)kb * N3 + mat * U_DIM + c) * 32 + r] = (__bf16)tile[r][c];
    }
}

// ---------------------------------------------------------------------------
// Kernel 2: fused gelu-feat + 3-way GEMM, split-K=8, XCD-pinned splits.
// grid = dim3(KSPL, TOK/BM3) = (8, 64); 1024 threads (16 waves: 4m x 4n).
// Each wave: 32 rows x 96 cols, K-slice = 1024. Writes bf16 partials.
// ---------------------------------------------------------------------------
__global__ __launch_bounds__(1024) void vsn_gemm3(
    const float* __restrict__ x,
    const float* __restrict__ fw,
    const float* __restrict__ fb,
    const __bf16* __restrict__ Bp,
    __bf16* __restrict__ Hp)
{
    __shared__ float  x_lds[BM3][9];          // 128 x (8+1) f32
    __shared__ __bf16 fw_lds[KRANGE];
    __shared__ __bf16 fb_lds[KRANGE];
    __shared__ __bf16 a_lds[2][BM3][ASTR];    // double-buffered A tile

    const int t    = threadIdx.x;
    const int wave = t >> 6;
    const int lane = t & 63;
    const int s     = blockIdx.x;             // k-split id -> XCD affinity
    const int tok0  = blockIdx.y * BM3;
    const int kbase = s * KRANGE;
    const int wm = wave >> 2;                 // 0..3 : row quad (32 rows)
    const int wn = wave & 3;                  // 0..3 : col quad (96 cols)
    const int lr  = lane & 15;
    const int lk8 = (lane >> 4) * 8;

    // ---- stage x slice (128 tok x 8 feat), fw/fb slice (1024 each)
    x_lds[t >> 3][t & 7] = x[(size_t)(tok0 + (t >> 3)) * F_DIM + (kbase >> 7) + (t & 7)];
    fw_lds[t] = (__bf16)fw[kbase + t];
    fb_lds[t] = (__bf16)fb[kbase + t];

    f32x4 acc[2][6];
#pragma unroll
    for (int i = 0; i < 2; ++i)
#pragma unroll
        for (int j = 0; j < 6; ++j)
            acc[i][j] = (f32x4){0.f, 0.f, 0.f, 0.f};

    const int m_a = t >> 3;          // 0..127: A row this thread computes
    const int kk  = (t & 7) * 8;     // 0..56 : A k-subcol (8 elems)

    auto gelu_write = [&](int st, int buf) {
        const int k0 = st * BK;
        const float xs = x_lds[m_a][(k0 + kk) >> 7];
        bf16x8 wv = *(const bf16x8*)&fw_lds[k0 + kk];
        bf16x8 bv = *(const bf16x8*)&fb_lds[k0 + kk];
        bf16x8 av;
#pragma unroll
        for (int j = 0; j < 8; ++j) {
            float z = fmaf(xs, (float)wv[j], (float)bv[j]);
            av[j] = (__bf16)gelu_fast(z);
        }
        *(bf16x8*)&a_lds[buf][m_a][kk] = av;
    };

    const __bf16* bb = Bp + (size_t)(kbase >> 5) * (N3 * 32)
                          + (size_t)(wn * 96 + lr) * 32 + lk8;

    __syncthreads();                 // staging visible
    gelu_write(0, 0);

    for (int st = 0; st < NST; ++st) {
        const int cur = st & 1;
        __syncthreads();             // a_lds[cur] ready; prior reads drained

        // B fragments: 12 coalesced 16B loads (L2-resident, XCD-local)
        bf16x8 bfrag[2][6];
#pragma unroll
        for (int ksi = 0; ksi < 2; ++ksi)
#pragma unroll
            for (int j = 0; j < 6; ++j)
                bfrag[ksi][j] = *(const bf16x8*)(bb
                    + (size_t)(st * 2 + ksi) * (N3 * 32) + j * 512);

        // next A tile's gelu overlaps the loads / MFMAs
        if (st + 1 < NST) gelu_write(st + 1, cur ^ 1);

#pragma unroll
        for (int ksi = 0; ksi < 2; ++ksi) {
            bf16x8 afrag[2];
#pragma unroll
            for (int i = 0; i < 2; ++i)
                afrag[i] = *(const bf16x8*)
                    &a_lds[cur][wm * 32 + i * 16 + lr][ksi * 32 + lk8];
#pragma unroll
            for (int i = 0; i < 2; ++i)
#pragma unroll
                for (int j = 0; j < 6; ++j)
                    acc[i][j] = __builtin_amdgcn_mfma_f32_16x16x32_bf16(
                        afrag[i], bfrag[ksi][j], acc[i][j], 0, 0, 0);
        }
    }

    // ---- write bf16 partials (C/D: col=lane&15, row=(lane>>4)*4+r)
    __bf16* Hs = Hp + (size_t)s * ((size_t)TOK * N3);
    const int r0 = (lane >> 4) * 4;
#pragma unroll
    for (int i = 0; i < 2; ++i)
#pragma unroll
        for (int j = 0; j < 6; ++j)
#pragma unroll
            for (int r = 0; r < 4; ++r)
                Hs[(size_t)(tok0 + wm * 32 + i * 16 + r0 + r) * N3
                   + wn * 96 + j * 16 + lr] = (__bf16)acc[i][j][r];
}

// ---------------------------------------------------------------------------
// Kernel 3: epilogue. grid = 512 WGs x 256 thr; 16 tokens/WG (4 per wave).
// lin_w staged in LDS (64KB, reused over 16 tokens); sm_w via L1.
// ---------------------------------------------------------------------------
__global__ __launch_bounds__(256) void vsn_epi3(
    const float* __restrict__ x,
    const __bf16* __restrict__ Hp,
    const float* __restrict__ elu_b,
    const float* __restrict__ lin_w,
    const float* __restrict__ lin_b,
    const float* __restrict__ gate_b,
    const float* __restrict__ ln_g,
    const float* __restrict__ ln_b,
    const float* __restrict__ sm_w,
    const float* __restrict__ sm_b,
    float* __restrict__ out)
{
    __shared__ float lin_lds[U_DIM * U_DIM];   // 64 KB
    __shared__ float sh[4][U_DIM];
    __shared__ float shy[4][U_DIM];

    const int t    = threadIdx.x;
    const int wave = t >> 6;
    const int lane = t & 63;
    const int tok0 = blockIdx.x * 16;

#pragma unroll 8
    for (int i = 0; i < 64; ++i)
        lin_lds[i * 256 + t] = lin_w[i * 256 + t];
    __syncthreads();

    for (int tk = 0; tk < 4; ++tk) {
        const int tok = tok0 + wave * 4 + tk;

        float a0 = 0.f, a1 = 0.f, g0 = 0.f, g1 = 0.f, p0 = 0.f, p1 = 0.f;
#pragma unroll
        for (int s = 0; s < KSPL; ++s) {
            const __bf16* Ht = Hp + (size_t)s * ((size_t)TOK * N3) + (size_t)tok * N3;
            a0 += (float)Ht[lane];        a1 += (float)Ht[64 + lane];
            g0 += (float)Ht[128 + lane];  g1 += (float)Ht[192 + lane];
            p0 += (float)Ht[256 + lane];  p1 += (float)Ht[320 + lane];
        }

        float e0 = a0 + elu_b[lane], e1 = a1 + elu_b[64 + lane];
        float h1_0 = (e0 > 0.f) ? e0 : expm1f(e0);
        float h1_1 = (e1 > 0.f) ? e1 : expm1f(e1);

        float gg0 = g0 + gate_b[lane], gg1 = g1 + gate_b[64 + lane];
        float gate0 = 1.0f / (1.0f + __expf(-gg0));
        float gate1 = 1.0f / (1.0f + __expf(-gg1));

        sh[wave][lane] = h1_0;
        sh[wave][64 + lane] = h1_1;
        __syncthreads();

        float h2_0 = lin_b[lane], h2_1 = lin_b[64 + lane];
#pragma unroll 4
        for (int v = 0; v < U_DIM; ++v) {
            float h1v = sh[wave][v];
            h2_0 = fmaf(h1v, lin_lds[v * U_DIM + lane],      h2_0);
            h2_1 = fmaf(h1v, lin_lds[v * U_DIM + 64 + lane], h2_1);
        }
        float h0 = gate0 * h2_0 + p0;
        float h1 = gate1 * h2_1 + p1;

        // LayerNorm over 128
        float sum = h0 + h1;
#pragma unroll
        for (int off = 32; off; off >>= 1) sum += __shfl_xor(sum, off);
        float mu = sum * (1.0f / 128.0f);
        float d0 = h0 - mu, d1 = h1 - mu;
        float vq = d0 * d0 + d1 * d1;
#pragma unroll
        for (int off = 32; off; off >>= 1) vq += __shfl_xor(vq, off);
        float rstd = rsqrtf(vq * (1.0f / 128.0f) + 1e-3f);
        float y0 = d0 * rstd * ln_g[lane]      + ln_b[lane];
        float y1 = d1 * rstd * ln_g[64 + lane] + ln_b[64 + lane];

        shy[wave][lane] = y0;
        shy[wave][64 + lane] = y1;
        __syncthreads();

        float lg = sm_b[lane];
#pragma unroll 4
        for (int u = 0; u < U_DIM; ++u)
            lg = fmaf(shy[wave][u], sm_w[u * F_DIM + lane], lg);

        float mx = lg;
#pragma unroll
        for (int off = 32; off; off >>= 1) mx = fmaxf(mx, __shfl_xor(mx, off));
        float ex = __expf(lg - mx);
        float se = ex;
#pragma unroll
        for (int off = 32; off; off >>= 1) se += __shfl_xor(se, off);
        float wgt = ex / se;

        float xv = x[(size_t)tok * F_DIM + lane];
        out[(size_t)tok * F_DIM + lane] = xv * wgt;
        out[(size_t)TOK * F_DIM + (size_t)tok * F_DIM + lane] = wgt;

        __syncthreads();   // sh/shy reuse safe next iteration
    }
}

// ---------------------------------------------------------------------------
extern "C" void kernel_launch(void* const* d_in, const int* in_sizes, int n_in,
                              void* d_out, int out_size, void* d_ws, size_t ws_size,
                              hipStream_t stream)
{
    const float* x      = (const float*)d_in[0];
    const float* fw     = (const float*)d_in[1];
    const float* fb     = (const float*)d_in[2];
    const float* elu_w  = (const float*)d_in[3];
    const float* elu_b  = (const float*)d_in[4];
    const float* lin_w  = (const float*)d_in[5];
    const float* lin_b  = (const float*)d_in[6];
    const float* gate_w = (const float*)d_in[7];
    const float* gate_b = (const float*)d_in[8];
    const float* proj_w = (const float*)d_in[9];
    const float* ln_g   = (const float*)d_in[10];
    const float* ln_b   = (const float*)d_in[11];
    const float* sm_w   = (const float*)d_in[12];
    const float* sm_b   = (const float*)d_in[13];

    // ws: Bp (6.29 MB) + 8 x bf16 partials (50.33 MB) = 56.62 MB
    // (same footprint as the round-2 f32/ksplit4 config that fit)
    __bf16* Bp = (__bf16*)d_ws;
    __bf16* Hp = (__bf16*)((char*)d_ws + (size_t)N3 * KDIM * sizeof(__bf16));

    vsn_prep3<<<3 * (KDIM / 32), 256, 0, stream>>>(elu_w, gate_w, proj_w, Bp);
    vsn_gemm3<<<dim3(KSPL, TOK / BM3), 1024, 0, stream>>>(x, fw, fb, Bp, Hp);
    vsn_epi3<<<TOK / 16, 256, 0, stream>>>(x, Hp, elu_b, lin_w, lin_b, gate_b,
                                           ln_g, ln_b, sm_w, sm_b, (float*)d_out);
}

// Round 4
// 104.611 us; speedup vs baseline: 1.5326x; 1.5326x over previous
//
#include <hip/hip_runtime.h>
#include <hip/hip_bf16.h>
#include <math.h>

// Problem dims
#define TOK   8192
#define KDIM  8192
#define F_DIM 64
#define U_DIM 128
#define N3    384

// GEMM tiling
#define BM    64
#define BK    64
#define KSPL  4
#define KRANGE (KDIM / KSPL)     // 2048
#define NST   (KRANGE / BK)      // 32
#define NF    (KRANGE / U_DIM)   // 16
#define ASTR  72

typedef __bf16 bf16x8 __attribute__((ext_vector_type(8)));
typedef float  f32x4  __attribute__((ext_vector_type(4)));

// raw barrier: drain LDS ops only; B-loads (vmcnt) stay in flight across it
#define WG_SYNC() do {                                       \
    asm volatile("s_waitcnt lgkmcnt(0)" ::: "memory");       \
    __builtin_amdgcn_s_barrier();                            \
    __builtin_amdgcn_sched_barrier(0);                       \
} while (0)

// tanh-approx GELU: z - z/(1 + 2^(z*(2.30234 + 0.102955 z^2))), |err| < ~1e-3
__device__ __forceinline__ float gelu_fast(float z) {
    float t = z * z;
    float s = fmaf(0.1029551f, t, 2.3023457f);
    float e = __builtin_amdgcn_exp2f(z * s);
    float r = __builtin_amdgcn_rcpf(e + 1.0f);   // +inf -> 0
    return fmaf(-z, r, z);
}

__device__ __forceinline__ float bflo(unsigned u) { u <<= 16; return __builtin_bit_cast(float, u); }
__device__ __forceinline__ float bfhi(unsigned u) { u &= 0xffff0000u; return __builtin_bit_cast(float, u); }

// ---------------------------------------------------------------------------
// Kernel 1: pack W[k][n] f32 (3 mats) -> Bp[k/32][n(384)][k%32] bf16,
// plus (block 768) lin_w -> bf16-pair-packed linp[128][64].
// grid = 3*(KDIM/32) + 1 = 769, 256 threads.
// ---------------------------------------------------------------------------
__global__ __launch_bounds__(256) void vsn_prep4(
    const float* __restrict__ elu_w,
    const float* __restrict__ gate_w,
    const float* __restrict__ proj_w,
    const float* __restrict__ lin_w,
    __bf16* __restrict__ Bp,
    unsigned* __restrict__ linp)
{
    const int t = threadIdx.x;
    if (blockIdx.x == 3 * (KDIM / 32)) {
        // pack lin_w [128][128] f32 -> linp [128][64] (2 bf16 per uint)
#pragma unroll
        for (int i = 0; i < 32; ++i) {
            int idx = i * 256 + t;            // 0..8191
            int v = idx >> 6, l = idx & 63;
            __bf16 ba = (__bf16)lin_w[v * U_DIM + 2 * l];
            __bf16 bb = (__bf16)lin_w[v * U_DIM + 2 * l + 1];
            unsigned pa = (unsigned)__builtin_bit_cast(unsigned short, ba);
            unsigned pb = (unsigned)__builtin_bit_cast(unsigned short, bb);
            linp[idx] = pa | (pb << 16);
        }
        return;
    }
    __shared__ float tile[32][U_DIM + 1];
    const int mat = blockIdx.x / (KDIM / 32);
    const int kb  = blockIdx.x % (KDIM / 32);
    const float* W = (mat == 0) ? elu_w : (mat == 1 ? gate_w : proj_w);

#pragma unroll
    for (int i = 0; i < 16; ++i) {
        int idx = i * 256 + t;
        int r = idx >> 7, c = idx & 127;
        tile[r][c] = W[(size_t)(kb * 32 + r) * U_DIM + c];
    }
    __syncthreads();
#pragma unroll
    for (int i = 0; i < 16; ++i) {
        int idx = i * 256 + t;
        int c = idx >> 5, r = idx & 31;
        Bp[((size_t)kb * N3 + mat * U_DIM + c) * 32 + r] = (__bf16)tile[r][c];
    }
}

// ---------------------------------------------------------------------------
// Kernel 2: fused gelu-feat + 3-way GEMM. grid = (KSPL=4, TOK/BM=128),
// 256 thr (4 waves, wave = 96 n-cols, acc[4][6] = 64 rows).
// XCD k gets ids==k (mod 8) -> bx = k%4: one k-split per XCD (B L2-resident).
// B software-pipelined half-step ahead; raw barrier keeps loads in flight.
// ---------------------------------------------------------------------------
__global__ __launch_bounds__(256, 2) void vsn_gemm4(
    const float* __restrict__ x,
    const float* __restrict__ fw,
    const float* __restrict__ fb,
    const __bf16* __restrict__ Bp,
    __bf16* __restrict__ Hp)
{
    __shared__ float  x_lds[BM][NF + 1];      // 64 x 17 f32
    __shared__ __bf16 fw_lds[KRANGE];         // 4 KB
    __shared__ __bf16 fb_lds[KRANGE];         // 4 KB
    __shared__ __bf16 a_lds[2][BM][ASTR];     // 18 KB dbuf

    const int t    = threadIdx.x;
    const int wave = t >> 6;
    const int lane = t & 63;
    const int s     = blockIdx.x;
    const int tok0  = blockIdx.y * BM;
    const int kbase = s * KRANGE;
    const int nbase = wave * 96;
    const int lr  = lane & 15;
    const int lk8 = (lane >> 4) * 8;

    // ---- stage x (64x16), fw/fb (2048 each)
#pragma unroll
    for (int i = 0; i < (BM * NF) / 256; ++i) {
        int idx = i * 256 + t;
        int r = idx >> 4, c = idx & 15;
        x_lds[r][c] = x[(size_t)(tok0 + r) * F_DIM + (kbase >> 7) + c];
    }
#pragma unroll
    for (int i = 0; i < KRANGE / 256; ++i) {
        int k = i * 256 + t;
        fw_lds[k] = (__bf16)fw[kbase + k];
        fb_lds[k] = (__bf16)fb[kbase + k];
    }

    f32x4 acc[4][6];
#pragma unroll
    for (int i = 0; i < 4; ++i)
#pragma unroll
        for (int j = 0; j < 6; ++j)
            acc[i][j] = (f32x4){0.f, 0.f, 0.f, 0.f};

    const int m_a = t >> 2;          // 0..63 : A row this thread computes
    const int kk  = (t & 3) * 16;    // 0..48 : A k-subcol (16 elems)

    auto gelu_write = [&](int st, int buf) {
        const int k0 = st * BK;
        const float xs = x_lds[m_a][(k0 + kk) >> 7];
#pragma unroll
        for (int h = 0; h < 2; ++h) {
            bf16x8 wv = *(const bf16x8*)&fw_lds[k0 + kk + h * 8];
            bf16x8 bv = *(const bf16x8*)&fb_lds[k0 + kk + h * 8];
            bf16x8 av;
#pragma unroll
            for (int j = 0; j < 8; ++j) {
                float z = fmaf(xs, (float)wv[j], (float)bv[j]);
                av[j] = (__bf16)gelu_fast(z);
            }
            *(bf16x8*)&a_lds[buf][m_a][kk + h * 8] = av;
        }
    };

    const __bf16* bb = Bp + (size_t)(kbase >> 5) * (N3 * 32)
                          + (nbase + lr) * 32 + lk8;
    auto loadB = [&](int st, int ksi, bf16x8 (&dst)[6]) {
        const __bf16* p = bb + (size_t)(st * 2 + ksi) * (N3 * 32);
#pragma unroll
        for (int j = 0; j < 6; ++j)
            dst[j] = *(const bf16x8*)(p + j * 512);
    };

    bf16x8 bX[6], bY[6];

    WG_SYNC();                     // staging visible
    gelu_write(0, 0);
    loadB(0, 0, bX);

    for (int st = 0; st < NST - 1; ++st) {
        const int cur = st & 1;
        WG_SYNC();                 // a_lds[cur] ready; buf cur^1 free
        loadB(st, 1, bY);          // issue ksi=1 loads (used after ~350 cy)
        gelu_write(st + 1, cur ^ 1);

        bf16x8 af[4];
#pragma unroll
        for (int i = 0; i < 4; ++i)
            af[i] = *(const bf16x8*)&a_lds[cur][i * 16 + lr][lk8];
#pragma unroll
        for (int i = 0; i < 4; ++i)
#pragma unroll
            for (int j = 0; j < 6; ++j)
                acc[i][j] = __builtin_amdgcn_mfma_f32_16x16x32_bf16(
                    af[i], bX[j], acc[i][j], 0, 0, 0);

        loadB(st + 1, 0, bX);      // prefetch next step's ksi=0
#pragma unroll
        for (int i = 0; i < 4; ++i)
            af[i] = *(const bf16x8*)&a_lds[cur][i * 16 + lr][32 + lk8];
#pragma unroll
        for (int i = 0; i < 4; ++i)
#pragma unroll
            for (int j = 0; j < 6; ++j)
                acc[i][j] = __builtin_amdgcn_mfma_f32_16x16x32_bf16(
                    af[i], bY[j], acc[i][j], 0, 0, 0);
    }
    {   // final step (st = NST-1, cur = 1): no next-tile gelu / prefetch
        const int cur = (NST - 1) & 1;
        WG_SYNC();
        loadB(NST - 1, 1, bY);
        bf16x8 af[4];
#pragma unroll
        for (int i = 0; i < 4; ++i)
            af[i] = *(const bf16x8*)&a_lds[cur][i * 16 + lr][lk8];
#pragma unroll
        for (int i = 0; i < 4; ++i)
#pragma unroll
            for (int j = 0; j < 6; ++j)
                acc[i][j] = __builtin_amdgcn_mfma_f32_16x16x32_bf16(
                    af[i], bX[j], acc[i][j], 0, 0, 0);
#pragma unroll
        for (int i = 0; i < 4; ++i)
            af[i] = *(const bf16x8*)&a_lds[cur][i * 16 + lr][32 + lk8];
#pragma unroll
        for (int i = 0; i < 4; ++i)
#pragma unroll
            for (int j = 0; j < 6; ++j)
                acc[i][j] = __builtin_amdgcn_mfma_f32_16x16x32_bf16(
                    af[i], bY[j], acc[i][j], 0, 0, 0);
    }

    // ---- write bf16 partials (C/D: col=lane&15, row=(lane>>4)*4+r)
    __bf16* Hs = Hp + (size_t)s * ((size_t)TOK * N3);
    const int r0 = (lane >> 4) * 4;
#pragma unroll
    for (int i = 0; i < 4; ++i)
#pragma unroll
        for (int j = 0; j < 6; ++j)
#pragma unroll
            for (int r = 0; r < 4; ++r)
                Hs[(size_t)(tok0 + i * 16 + r0 + r) * N3 + nbase + j * 16 + lr]
                    = (__bf16)acc[i][j][r];
}

// ---------------------------------------------------------------------------
// Kernel 3: epilogue. grid = TOK/16 = 512 WGs x 256 thr; wave = 4 tokens.
// Lane l owns feature pair (2l, 2l+1); shfl-broadcast matmuls over 4 tokens.
// ---------------------------------------------------------------------------
__global__ __launch_bounds__(256) void vsn_epi4(
    const float* __restrict__ x,
    const __bf16* __restrict__ Hp,
    const unsigned* __restrict__ linp,
    const float* __restrict__ elu_b,
    const float* __restrict__ lin_b,
    const float* __restrict__ gate_b,
    const float* __restrict__ ln_g,
    const float* __restrict__ ln_b,
    const float* __restrict__ sm_w,
    const float* __restrict__ sm_b,
    float* __restrict__ out)
{
    __shared__ unsigned lin_lds[U_DIM * 64];     // 32 KB (bf16 pairs)
    __shared__ float    smw_lds[U_DIM * F_DIM];  // 32 KB
    const int t = threadIdx.x, wave = t >> 6, lane = t & 63;
    const int tokb = blockIdx.x * 16 + wave * 4;

    {
        const uint4* l4 = (const uint4*)linp;
        uint4* d4 = (uint4*)lin_lds;
#pragma unroll
        for (int i = 0; i < 8; ++i) d4[i * 256 + t] = l4[i * 256 + t];
        const f32x4* s4 = (const f32x4*)sm_w;
        f32x4* m4 = (f32x4*)smw_lds;
#pragma unroll
        for (int i = 0; i < 8; ++i) m4[i * 256 + t] = s4[i * 256 + t];
    }
    __syncthreads();

    const float2 eb  = *(const float2*)&elu_b[2 * lane];
    const float2 gb  = *(const float2*)&gate_b[2 * lane];
    const float2 lb  = *(const float2*)&lin_b[2 * lane];
    const float2 lg2 = *(const float2*)&ln_g[2 * lane];
    const float2 lnb = *(const float2*)&ln_b[2 * lane];
    const float  smb = sm_b[lane];

    float h1a[4], h1b[4], ga[4], gbt[4], pa[4], pb[4];
#pragma unroll
    for (int tk = 0; tk < 4; ++tk) {
        const unsigned short* base =
            (const unsigned short*)Hp + (size_t)(tokb + tk) * N3;
        float a0 = 0.f, a1 = 0.f, g0 = 0.f, g1 = 0.f, p0 = 0.f, p1 = 0.f;
#pragma unroll
        for (int s = 0; s < KSPL; ++s) {
            const unsigned short* bs = base + (size_t)s * TOK * N3;
            unsigned ua = *(const unsigned*)(bs + 2 * lane);
            unsigned ug = *(const unsigned*)(bs + 128 + 2 * lane);
            unsigned up = *(const unsigned*)(bs + 256 + 2 * lane);
            a0 += bflo(ua); a1 += bfhi(ua);
            g0 += bflo(ug); g1 += bfhi(ug);
            p0 += bflo(up); p1 += bfhi(up);
        }
        float e0 = a0 + eb.x, e1 = a1 + eb.y;
        h1a[tk] = (e0 > 0.f) ? e0 : expm1f(e0);
        h1b[tk] = (e1 > 0.f) ? e1 : expm1f(e1);
        ga[tk]  = 1.f / (1.f + __expf(-(g0 + gb.x)));
        gbt[tk] = 1.f / (1.f + __expf(-(g1 + gb.y)));
        pa[tk] = p0; pb[tk] = p1;
    }

    // h2 = h1 @ lin_w + lin_b  (shfl-broadcast, 4 tokens jointly)
    float h2a[4] = {lb.x, lb.x, lb.x, lb.x};
    float h2b[4] = {lb.y, lb.y, lb.y, lb.y};
#pragma unroll 2
    for (int v = 0; v < U_DIM; v += 2) {
        unsigned lwA = lin_lds[v * 64 + lane];
        unsigned lwB = lin_lds[(v + 1) * 64 + lane];
        float wAx = bflo(lwA), wAy = bfhi(lwA);
        float wBx = bflo(lwB), wBy = bfhi(lwB);
        const int src = v >> 1;
#pragma unroll
        for (int tk = 0; tk < 4; ++tk) {
            float hvA = __shfl(h1a[tk], src);
            float hvB = __shfl(h1b[tk], src);
            h2a[tk] = fmaf(hvA, wAx, fmaf(hvB, wBx, h2a[tk]));
            h2b[tk] = fmaf(hvA, wAy, fmaf(hvB, wBy, h2b[tk]));
        }
    }

    // gate/residual + LayerNorm -> y pairs
    float ya[4], yb[4];
#pragma unroll
    for (int tk = 0; tk < 4; ++tk) {
        float h0 = ga[tk] * h2a[tk] + pa[tk];
        float h1 = gbt[tk] * h2b[tk] + pb[tk];
        float sum = h0 + h1;
#pragma unroll
        for (int off = 32; off; off >>= 1) sum += __shfl_xor(sum, off);
        float mu = sum * (1.0f / 128.0f);
        float d0 = h0 - mu, d1 = h1 - mu;
        float vq = d0 * d0 + d1 * d1;
#pragma unroll
        for (int off = 32; off; off >>= 1) vq += __shfl_xor(vq, off);
        float rstd = rsqrtf(vq * (1.0f / 128.0f) + 1e-3f);
        ya[tk] = d0 * rstd * lg2.x + lnb.x;
        yb[tk] = d1 * rstd * lg2.y + lnb.y;
    }

    // logits = y @ sm_w + sm_b  (lane = feature f)
    float lgt[4] = {smb, smb, smb, smb};
#pragma unroll 2
    for (int u = 0; u < U_DIM; u += 2) {
        float swA = smw_lds[u * F_DIM + lane];
        float swB = smw_lds[(u + 1) * F_DIM + lane];
        const int src = u >> 1;
#pragma unroll
        for (int tk = 0; tk < 4; ++tk) {
            float yvA = __shfl(ya[tk], src);
            float yvB = __shfl(yb[tk], src);
            lgt[tk] = fmaf(yvA, swA, fmaf(yvB, swB, lgt[tk]));
        }
    }

    // softmax over 64 lanes + outputs
#pragma unroll
    for (int tk = 0; tk < 4; ++tk) {
        const int tok = tokb + tk;
        float mx = lgt[tk];
#pragma unroll
        for (int off = 32; off; off >>= 1) mx = fmaxf(mx, __shfl_xor(mx, off));
        float ex = __expf(lgt[tk] - mx);
        float se = ex;
#pragma unroll
        for (int off = 32; off; off >>= 1) se += __shfl_xor(se, off);
        float wgt = ex / se;
        float xv = x[(size_t)tok * F_DIM + lane];
        out[(size_t)tok * F_DIM + lane] = xv * wgt;
        out[(size_t)TOK * F_DIM + (size_t)tok * F_DIM + lane] = wgt;
    }
}

// ---------------------------------------------------------------------------
extern "C" void kernel_launch(void* const* d_in, const int* in_sizes, int n_in,
                              void* d_out, int out_size, void* d_ws, size_t ws_size,
                              hipStream_t stream)
{
    const float* x      = (const float*)d_in[0];
    const float* fw     = (const float*)d_in[1];
    const float* fb     = (const float*)d_in[2];
    const float* elu_w  = (const float*)d_in[3];
    const float* elu_b  = (const float*)d_in[4];
    const float* lin_w  = (const float*)d_in[5];
    const float* lin_b  = (const float*)d_in[6];
    const float* gate_w = (const float*)d_in[7];
    const float* gate_b = (const float*)d_in[8];
    const float* proj_w = (const float*)d_in[9];
    const float* ln_g   = (const float*)d_in[10];
    const float* ln_b   = (const float*)d_in[11];
    const float* sm_w   = (const float*)d_in[12];
    const float* sm_b   = (const float*)d_in[13];

    // ws: Bp 6.29 MB | Hp (4 x bf16 partials) 25.17 MB | linp 32 KB = 31.5 MB
    char* wsb = (char*)d_ws;
    __bf16*   Bp   = (__bf16*)wsb;
    __bf16*   Hp   = (__bf16*)(wsb + (size_t)N3 * KDIM * sizeof(__bf16));
    unsigned* linp = (unsigned*)(wsb + (size_t)N3 * KDIM * sizeof(__bf16)
                                     + (size_t)KSPL * TOK * N3 * sizeof(__bf16));

    vsn_prep4<<<3 * (KDIM / 32) + 1, 256, 0, stream>>>(elu_w, gate_w, proj_w,
                                                       lin_w, Bp, linp);
    vsn_gemm4<<<dim3(KSPL, TOK / BM), 256, 0, stream>>>(x, fw, fb, Bp, Hp);
    vsn_epi4<<<TOK / 16, 256, 0, stream>>>(x, Hp, linp, elu_b, lin_b, gate_b,
                                           ln_g, ln_b, sm_w, sm_b, (float*)d_out);
}